// Round 3
// baseline (2915.784 us; speedup 1.0000x reference)
//
#include <hip/hip_runtime.h>

// Problem dims (fp32 in / fp32 out)
#define B_    64
#define T_    512
#define DIN_  256
#define H_    512
#define DOUT_ 128

// Pipeline chunking: layer-1 consumes layer-0's output CHUNK timesteps at a time.
#define CHUNK  32
#define NCHUNK (T_ / CHUNK)     // 16
#define NGEMM  64               // gemm-worker WGs: (B_*CHUNK/128) M-tiles * (H_/128) N-tiles = 16*4

typedef _Float16 f16x8 __attribute__((ext_vector_type(8)));
typedef float    f32x4 __attribute__((ext_vector_type(4)));
typedef _Float16 half2v __attribute__((ext_vector_type(2)));

// ---------------------------------------------------------------------------
// dot of 8 f16 pairs (w,h packed as uint4) accumulated into fp32
__device__ __forceinline__ float dot8(uint4 w, uint4 h, float s) {
#if __has_builtin(__builtin_amdgcn_fdot2)
  s = __builtin_amdgcn_fdot2(__builtin_bit_cast(half2v, w.x), __builtin_bit_cast(half2v, h.x), s, false);
  s = __builtin_amdgcn_fdot2(__builtin_bit_cast(half2v, w.y), __builtin_bit_cast(half2v, h.y), s, false);
  s = __builtin_amdgcn_fdot2(__builtin_bit_cast(half2v, w.z), __builtin_bit_cast(half2v, h.z), s, false);
  s = __builtin_amdgcn_fdot2(__builtin_bit_cast(half2v, w.w), __builtin_bit_cast(half2v, h.w), s, false);
#else
  const half2v* wp = (const half2v*)&w;
  const half2v* hp = (const half2v*)&h;
#pragma unroll
  for (int q = 0; q < 4; ++q) {
    s += (float)wp[q][0] * (float)hp[q][0] + (float)wp[q][1] * (float)hp[q][1];
  }
#endif
  return s;
}

// fast branchless tanh: tanh(x) = sign(x) * (1 - 2/(e^{2|x|}+1)); |err| ~1e-6
__device__ __forceinline__ float fast_tanh(float x) {
  float a = fabsf(x);
  float e = __expf(2.f * a);
  float r = 1.f - 2.f / (e + 1.f);
  return copysignf(r, x);
}

// opaque pin: forces v's components into arch VGPRs at this point and makes
// the producing loads non-rematerializable
__device__ __forceinline__ void pin4(uint4& v) {
  asm volatile("" : "+v"(v.x), "+v"(v.y), "+v"(v.z), "+v"(v.w));
}

// LDS-only barrier: drains own ds ops (lgkmcnt) then syncs, WITHOUT the
// vmcnt(0) drain __syncthreads emits — in-flight global W-ring loads
// (register destinations only) legally stay outstanding across it.
__device__ __forceinline__ void barrier_lds() {
  asm volatile("s_waitcnt lgkmcnt(0)" ::: "memory");
  __builtin_amdgcn_s_barrier();
}

// device-scope (agent) flag ops for the chunk pipeline
__device__ __forceinline__ unsigned ld_flag(const unsigned* p) {
  return __hip_atomic_load(p, __ATOMIC_RELAXED, __HIP_MEMORY_SCOPE_AGENT);
}
__device__ __forceinline__ void add_flag(unsigned* p) {
  __hip_atomic_fetch_add(p, 1u, __ATOMIC_RELEASE, __HIP_MEMORY_SCOPE_AGENT);
}
__device__ __forceinline__ void wait_flag(const unsigned* p, unsigned target) {
  // bounded spin: capacity argument guarantees progress (192 WGs <= 256 CUs,
  // 1 WG/CU forced by VGPR count, producers never wait on consumers).
  for (int n = 0; n < (1 << 21); ++n) {
    if (ld_flag(p) >= target) return;
    __builtin_amdgcn_s_sleep(8);
  }
}

// ---------------------------------------------------------------------------
// Generic fp32 -> f16 conversion (memory-bound, one-shot prep)
__global__ void cvt_f32_f16(const float* __restrict__ in, _Float16* __restrict__ out, int n) {
  int idx = blockIdx.x * 256 + threadIdx.x;
  if (idx < n) out[idx] = (_Float16)in[idx];
}

__global__ void zero_flags(unsigned* __restrict__ f) {
  if (threadIdx.x < 2 * NCHUNK) f[threadIdx.x] = 0u;
}

// ---------------------------------------------------------------------------
// Prep: convert W_hh (fp32, row-major HxH) into the R3 scan layout:
// thread tid owns rows 8*(tid&63)+s (s=0..7) over k-eighth u=tid>>6.
// Slot (s,i): slot = s*8+i (i = col-chunk of 8 within the 64-wide eighth).
// chunk c = slot*512 + tid  holds  W[8*(tid&63)+s][(tid>>6)*64 + i*8 .. +8)
// Scan thread tid loads chunk (s,i) at lane-stride 16 B -> fully coalesced.
__global__ void prep_w(const float* __restrict__ w0, const float* __restrict__ w1,
                       _Float16* __restrict__ o0, _Float16* __restrict__ o1) {
  int idx = blockIdx.x * 256 + threadIdx.x;        // 0 .. 65535 (two matrices)
  const float* src = (idx < 32768) ? w0 : w1;
  _Float16* dst = (idx < 32768) ? o0 : o1;
  int c = idx & 32767;
  int tid  = c & 511;
  int slot = c >> 9;          // 0..63
  int i = slot & 7;
  int s = slot >> 3;          // 0..7
  int row = 8 * (tid & 63) + s;
  int kc  = (tid >> 6) * 8 + i;
#pragma unroll
  for (int e = 0; e < 8; ++e)
    dst[(size_t)c * 8 + e] = (_Float16)src[row * 512 + kc * 8 + e];
}

// ---------------------------------------------------------------------------
// GEMM: out[m,n] = sum_k X[m,k]*W[n,k] + bias1[n] + bias2[n], written as f16.
// 128x128 tile / 256 threads / 4 waves (2x2 of 64x64), BK=32 (for xproj0 only).
__global__ __launch_bounds__(256)
void gemm_xproj(const _Float16* __restrict__ X,
                const _Float16* __restrict__ W,
                const float* __restrict__ bias1,
                const float* __restrict__ bias2,
                _Float16* __restrict__ out, int K) {
  __shared__ __align__(16) _Float16 As[128 * 32];
  __shared__ __align__(16) _Float16 Bs[128 * 32];
  const int tid  = threadIdx.x;
  const int wave = tid >> 6;
  const int lane = tid & 63;
  const int wr = wave >> 1, wc = wave & 1;
  const int m0 = blockIdx.x * 128, n0 = blockIdx.y * 128;
  const int fr = lane & 15;
  const int fk = (lane >> 4) * 8;
  const int cA = (lane & 3) * 8;
  const int rsub = lane >> 2;

  f32x4 acc[4][4];
#pragma unroll
  for (int a = 0; a < 4; ++a)
#pragma unroll
    for (int b = 0; b < 4; ++b)
      acc[a][b] = (f32x4){0.f, 0.f, 0.f, 0.f};

  for (int k0 = 0; k0 < K; k0 += 32) {
    __syncthreads();
#pragma unroll
    for (int q = 0; q < 2; ++q) {
      int p = wave * 2 + q;
      int r = p * 16 + rsub;
      const _Float16* gA = X + (size_t)(m0 + r) * K + (k0 + cA);
      const _Float16* gB = W + (size_t)(n0 + r) * K + (k0 + cA);
      __builtin_amdgcn_global_load_lds(
          (const __attribute__((address_space(1))) void*)gA,
          (__attribute__((address_space(3))) void*)((char*)As + p * 1024), 16, 0, 0);
      __builtin_amdgcn_global_load_lds(
          (const __attribute__((address_space(1))) void*)gB,
          (__attribute__((address_space(3))) void*)((char*)Bs + p * 1024), 16, 0, 0);
    }
    __syncthreads();

    f16x8 af[4], bfr[4];
#pragma unroll
    for (int mt = 0; mt < 4; ++mt)
      af[mt] = *(const f16x8*)&As[(wr * 64 + mt * 16 + fr) * 32 + fk];
#pragma unroll
    for (int nt = 0; nt < 4; ++nt)
      bfr[nt] = *(const f16x8*)&Bs[(wc * 64 + nt * 16 + fr) * 32 + fk];
#pragma unroll
    for (int mt = 0; mt < 4; ++mt)
#pragma unroll
      for (int nt = 0; nt < 4; ++nt)
        acc[mt][nt] = __builtin_amdgcn_mfma_f32_16x16x32_f16(af[mt], bfr[nt], acc[mt][nt], 0, 0, 0);
  }

  const int col = lane & 15, rq = lane >> 4;
#pragma unroll
  for (int nt = 0; nt < 4; ++nt) {
    int n = n0 + wc * 64 + nt * 16 + col;
    float bias = bias1[n] + bias2[n];
#pragma unroll
    for (int mt = 0; mt < 4; ++mt) {
      int mbase = m0 + wr * 64 + mt * 16 + rq * 4;
#pragma unroll
      for (int r = 0; r < 4; ++r)
        out[(size_t)(mbase + r) * H_ + n] = (_Float16)(acc[mt][nt][r] + bias);
    }
  }
}

// ---------------------------------------------------------------------------
// Scan role, R3 restructure: 8 k-eighths (u = wave = tid>>6), 8 rows/thread
// (rows 8r+s, r = tid&63, s = 0..7), K=64 per thread.
//   slots  0..39 (s=0..4)  -> 40 uint4 = 160 VGPR register-resident
//                             (VGPR>128 also hard-forces 1 WG/CU)
//   slots 40..63 (s=5..7)  -> streamed from L2, three 2-deep rings with
//                             wrap-around reload ((i+2)&7): next step's first
//                             loads issue during this step's tail.
// Per-step LDS/CU: h-broadcast 8 waves x 8 b128 = 768 cyc (was 1536),
// ldsW 0 (was 576), psum 2x b128 write dense + 8 b32 read 2-way ~= 560.
__device__ __forceinline__ void scan_role(
    int layer, int b,
    const uint4* __restrict__ Wg, const _Float16* __restrict__ xproj,
    _Float16* __restrict__ seq, float* __restrict__ hlast,
    unsigned* __restrict__ ca, unsigned* __restrict__ cb, char* smem)
{
  float* psumA = (float*)smem;                                 // [8][256] 8 KB (rows 8r+0..3)
  float* psumB = (float*)(smem + 8192);                        // [8][256] 8 KB (rows 8r+4..7)
  _Float16 (*hb)[512] = (_Float16 (*)[512])(smem + 16384);     // 2 KB h double buffer
  const int tid = threadIdx.x;
  const int u = tid >> 6;                                      // k-eighth 0..7 (= wave)
  const int r = tid & 63;

  // slots 0..39 (s=0..4) -> 160 VGPRs, coalesced (lane stride 16 B)
  uint4 wreg[40];
#pragma unroll
  for (int i = 0; i < 40; ++i) wreg[i] = Wg[i * 512 + tid];
#pragma unroll
  for (int i = 0; i < 40; ++i) pin4(wreg[i]);

  hb[0][tid] = (_Float16)0.f;
  hb[1][tid] = (_Float16)0.f;
  __syncthreads();

  const uint4* S5 = Wg + (size_t)40 * 512 + tid;    // s=5, i=0..7
  const uint4* S6 = Wg + (size_t)48 * 512 + tid;    // s=6, i=0..7
  const uint4* S7 = Wg + (size_t)56 * 512 + tid;    // s=7, i=0..7
  const _Float16* xp = xproj + (size_t)b * (T_ * H_) + tid;
  _Float16* sq = seq + (size_t)b * (T_ * H_) + tid;

  // prime the rings once; in-loop reload wraps ((i+2)&7) so they self-sustain
  uint4 q5[2], q6[2], q7[2];
  q5[0] = S5[0];            q5[1] = S5[512];
  q6[0] = S6[0];            q6[1] = S6[512];
  q7[0] = S7[0];            q7[1] = S7[512];

  // reduce-phase base: thread tid owns row tid = 8*(tid>>3)+(tid&7)
  const float* pred = ((tid & 4) ? psumB : psumA) + 4 * (tid >> 3) + (tid & 3);

  int cur = 0;
  for (int t = 0; t < T_; ++t) {
    if (layer == 1 && (t & (CHUNK - 1)) == 0) {
      // acquire chunk t/CHUNK of xproj1
      if (tid == 0) wait_flag(cb + (t / CHUNK), NGEMM);
      __syncthreads();
      __threadfence();                              // inv stale L1/L2 lines
    }
    float xv = (float)xp[(size_t)t * H_];           // consumed after barrier A
    const uint4* hbu = (const uint4*)hb[cur] + u * 8;

    float a0 = 0.f, a1 = 0.f, a2 = 0.f, a3 = 0.f;
    float a4 = 0.f, a5 = 0.f, a6 = 0.f, a7 = 0.f;
#pragma unroll
    for (int i = 0; i < 8; ++i) {
      uint4 h = hbu[i];                             // one b128 broadcast read
      a0 = dot8(wreg[i],      h, a0);
      a1 = dot8(wreg[8 + i],  h, a1);
      a2 = dot8(wreg[16 + i], h, a2);
      a3 = dot8(wreg[24 + i], h, a3);
      a4 = dot8(wreg[32 + i], h, a4);
      a5 = dot8(q5[i & 1], h, a5);
      q5[i & 1] = S5[(size_t)((i + 2) & 7) * 512];
      a6 = dot8(q6[i & 1], h, a6);
      q6[i & 1] = S6[(size_t)((i + 2) & 7) * 512];
      a7 = dot8(q7[i & 1], h, a7);
      q7[i & 1] = S7[(size_t)((i + 2) & 7) * 512];
    }
    // two dense b128 stores (lane stride 16 B -> conflict-free)
    *(f32x4*)&psumA[u * 256 + 4 * r] = (f32x4){a0, a1, a2, a3};
    *(f32x4*)&psumB[u * 256 + 4 * r] = (f32x4){a4, a5, a6, a7};
    barrier_lds();                                  // A: partials visible

    // reduce: thread tid owns row tid; A/B halves alias banks 2-way (free)
    float s = (((pred[0] + pred[256]) + (pred[512] + pred[768])) +
               ((pred[1024] + pred[1280]) + (pred[1536] + pred[1792])));
    float hn = fast_tanh(s + xv);
    _Float16 h16 = (_Float16)hn;
    hb[cur ^ 1][tid] = h16;
    if (layer == 0) {
      sq[(size_t)t * H_] = h16;
    } else if (t == T_ - 1) {
      hlast[b * H_ + tid] = hn;
    }
    if (layer == 0 && (t & (CHUNK - 1)) == CHUNK - 1) {
      // need the seq stores drained before publishing -> full syncthreads
      __syncthreads();
      if (tid == 0) { __threadfence(); add_flag(ca + (t / CHUNK)); }
    } else {
      barrier_lds();                                // B: hb[cur^1] complete
    }
    cur ^= 1;
  }
}

// ---------------------------------------------------------------------------
// GEMM worker role: per chunk c, WG g computes one 128x128 tile of
// xproj1 = h1seq @ W_ih1^T + b_ih1 + b_hh1, writing IN PLACE over xproj0
// (safe: runs only after all L0 WGs finished — and thus finished reading —
// chunk c). 512 threads = 8 waves as 4x2 grid of 32x64 fragments.
__device__ __forceinline__ void gemm_role(
    int g,
    const _Float16* __restrict__ X,      // h1seq  (B,T,H) f16
    const _Float16* __restrict__ W,      // W_ih1  (H,H)   f16
    const float* __restrict__ bias1, const float* __restrict__ bias2,
    _Float16* __restrict__ out,          // xproj  (B,T,H) f16 (in-place)
    unsigned* __restrict__ ca, unsigned* __restrict__ cb, char* smem)
{
  _Float16* As = (_Float16*)smem;              // 8 KB [128][32]
  _Float16* Bs = (_Float16*)(smem + 8192);     // 8 KB [128][32]
  const int tid  = threadIdx.x;
  const int wave = tid >> 6;
  const int lane = tid & 63;
  const int wr = wave >> 1, wc = wave & 1;     // 4x2 waves, each 32 rows x 64 cols
  const int mt = g >> 2;                       // M-tile 0..15 (128 rows of 2048)
  const int n0 = (g & 3) * 128;
  const int fr = lane & 15;
  const int fk = (lane >> 4) * 8;
  const int sr  = tid >> 2;                    // staging row 0..127
  const int scq = (tid & 3) * 8;               // staging col (f16) 0/8/16/24
  const int col = lane & 15, rq = lane >> 4;
  const size_t wrow = (size_t)(n0 + sr) * H_ + scq;   // W staging addr (chunk-invariant)

  for (int c = 0; c < NCHUNK; ++c) {
    if (tid == 0) wait_flag(ca + c, B_);       // all 64 L0 WGs done with chunk c
    __syncthreads();
    __threadfence();                           // inv stale lines before reading h1seq

    // tile row jj -> batch 4*mt + (jj>>5), t = c*CHUNK + (jj&31)
    const size_t arow =
        ((size_t)(4 * mt + (sr >> 5)) * T_ + c * CHUNK + (sr & 31)) * H_ + scq;

    f32x4 acc[2][4];
#pragma unroll
    for (int m = 0; m < 2; ++m)
#pragma unroll
      for (int n = 0; n < 4; ++n)
        acc[m][n] = (f32x4){0.f, 0.f, 0.f, 0.f};

    for (int k0 = 0; k0 < H_; k0 += 32) {
      __syncthreads();
      __builtin_amdgcn_global_load_lds(
          (const __attribute__((address_space(1))) void*)(X + arow + k0),
          (__attribute__((address_space(3))) void*)((char*)As + (tid >> 6) * 1024), 16, 0, 0);
      __builtin_amdgcn_global_load_lds(
          (const __attribute__((address_space(1))) void*)(W + wrow + k0),
          (__attribute__((address_space(3))) void*)((char*)Bs + (tid >> 6) * 1024), 16, 0, 0);
      __syncthreads();                         // plain: NEEDS the vmcnt drain

      f16x8 af[2], bf[4];
#pragma unroll
      for (int m = 0; m < 2; ++m)
        af[m] = *(const f16x8*)&As[(wr * 32 + m * 16 + fr) * 32 + fk];
#pragma unroll
      for (int n = 0; n < 4; ++n)
        bf[n] = *(const f16x8*)&Bs[(wc * 64 + n * 16 + fr) * 32 + fk];
#pragma unroll
      for (int m = 0; m < 2; ++m)
#pragma unroll
        for (int n = 0; n < 4; ++n)
          acc[m][n] = __builtin_amdgcn_mfma_f32_16x16x32_f16(af[m], bf[n], acc[m][n], 0, 0, 0);
    }

#pragma unroll
    for (int n = 0; n < 4; ++n) {
      int nn = n0 + wc * 64 + n * 16 + col;
      float bias = bias1[nn] + bias2[nn];
#pragma unroll
      for (int m = 0; m < 2; ++m) {
        int jbase = wr * 32 + m * 16 + rq * 4;
#pragma unroll
        for (int r = 0; r < 4; ++r) {
          int jj = jbase + r;
          size_t row = ((size_t)(4 * mt + (jj >> 5)) * T_ + c * CHUNK + (jj & 31)) * (size_t)H_;
          out[row + nn] = (_Float16)(acc[m][n][r] + bias);
        }
      }
    }
    __syncthreads();                           // drain all threads' tile stores
    if (tid == 0) { __threadfence(); add_flag(cb + c); }
  }
}

// ---------------------------------------------------------------------------
// Fused pipeline megakernel: 192 WGs x 512 threads, __launch_bounds__(512,1).
//   WG   0..63  : layer-0 scan (batch b)       — produces h1seq chunk flags ca[]
//   WG  64..127 : layer-1 scan (batch b-64)    — consumes xproj1 chunk flags cb[]
//   WG 128..191 : GEMM workers                 — ca[c] -> xproj1 tile -> cb[c]
// VGPR_Count > 128 (160 pinned W regs) forces 1 WG/CU: 192 WGs <= 256 CUs
// all co-resident, one per CU; the wait DAG (L1 <- GEMM <- L0) is acyclic.
__global__ __launch_bounds__(512, 1)
void fused_pipeline(const uint4* __restrict__ Wg0, const uint4* __restrict__ Wg1,
                    const _Float16* __restrict__ Wih1,
                    const float* __restrict__ b_ih1, const float* __restrict__ b_hh1,
                    _Float16* __restrict__ xproj, _Float16* __restrict__ h1seq,
                    float* __restrict__ hlast, unsigned* __restrict__ flags) {
  __shared__ __align__(16) char smem[18432];
  unsigned* ca = flags;            // [NCHUNK] target B_
  unsigned* cb = flags + NCHUNK;   // [NCHUNK] target NGEMM
  const int wg = blockIdx.x;
  if (wg < 64) {
    scan_role(0, wg, Wg0, xproj, h1seq, hlast, ca, cb, smem);
  } else if (wg < 128) {
    scan_role(1, wg - 64, Wg1, xproj, h1seq, hlast, ca, cb, smem);
  } else {
    gemm_role(wg - 128, h1seq, Wih1, b_ih1, b_hh1, xproj, ca, cb, smem);
  }
}

// ---------------------------------------------------------------------------
// Final FC: out[b,o] = h2[b,:] . w_fc[o,:] + b_fc[o]   (64 x 128, tiny, pure fp32)
__global__ void fc_kernel(const float* __restrict__ h2,
                          const float* __restrict__ wfc,
                          const float* __restrict__ bfc,
                          float* __restrict__ out) {
  int b = blockIdx.x, o = threadIdx.x;
  float s = bfc[o];
  const float* hv = h2 + b * H_;
  const float* wr = wfc + (size_t)o * H_;
#pragma unroll 8
  for (int k = 0; k < H_; ++k) s += hv[k] * wr[k];
  out[b * DOUT_ + o] = s;
}

// ---------------------------------------------------------------------------
extern "C" void kernel_launch(void* const* d_in, const int* in_sizes, int n_in,
                              void* d_out, int out_size, void* d_ws, size_t ws_size,
                              hipStream_t stream) {
  const float* x     = (const float*)d_in[0];
  const float* w_ih0 = (const float*)d_in[1];
  const float* w_hh0 = (const float*)d_in[2];
  const float* b_ih0 = (const float*)d_in[3];
  const float* b_hh0 = (const float*)d_in[4];
  const float* w_ih1 = (const float*)d_in[5];
  const float* w_hh1 = (const float*)d_in[6];
  const float* b_ih1 = (const float*)d_in[7];
  const float* b_hh1 = (const float*)d_in[8];
  const float* w_fc  = (const float*)d_in[9];
  const float* b_fc  = (const float*)d_in[10];

  char* ws = (char*)d_ws;
  _Float16* Ws0   = (_Float16*)(ws + 0);          // 512 KB  (w_hh0 scan layout)
  _Float16* Ws1   = (_Float16*)(ws + 524288);     // 512 KB  (w_hh1 scan layout)
  _Float16* Wih0  = (_Float16*)(ws + 1048576);    // 256 KB  (w_ih0 f16)
  _Float16* Wih1  = (_Float16*)(ws + 1310720);    // 512 KB  (w_ih1 f16)
  float*    h2    = (float*)   (ws + 2097152);    // 128 KB  (final hidden, fp32)
  unsigned* flags = (unsigned*)(ws + 3145728);    // 128 B   (chunk counters)
  _Float16* xproj = (_Float16*)(ws + 4194304);    // 32 MB   (xproj0, overwritten by xproj1)
  _Float16* xf16  = (_Float16*)(ws + 37748736);   // x as f16, then dead...
  _Float16* h1seq = (_Float16*)(ws + 37748736);   // ...h1 sequence f16 (32 MB)

  // 1) one-shot conversions to f16 + flag reset (re-zeroed every graph iteration)
  cvt_f32_f16<<<32768, 256, 0, stream>>>(x, xf16, B_ * T_ * DIN_);
  cvt_f32_f16<<<512,   256, 0, stream>>>(w_ih0, Wih0, H_ * DIN_);
  cvt_f32_f16<<<1024,  256, 0, stream>>>(w_ih1, Wih1, H_ * H_);
  prep_w<<<256, 256, 0, stream>>>(w_hh0, w_hh1, Ws0, Ws1);
  zero_flags<<<1, 64, 0, stream>>>(flags);

  // 2) xproj0 = x @ w_ih0^T + b_ih0 + b_hh0   (M=32768, K=256)
  gemm_xproj<<<dim3(256, 4), 256, 0, stream>>>(xf16, Wih0, b_ih0, b_hh0, xproj, DIN_);

  // 3+4+5) fused: layer-0 scan || chunked xproj1 GEMM || layer-1 scan
  fused_pipeline<<<192, 512, 0, stream>>>((const uint4*)Ws0, (const uint4*)Ws1,
                                          Wih1, b_ih1, b_hh1,
                                          xproj, h1seq, h2, flags);

  // 6) FC -> d_out (fp32, 64x128)
  fc_kernel<<<B_, DOUT_, 0, stream>>>(h2, w_fc, b_fc, (float*)d_out);
}

// Round 4
// 1487.074 us; speedup vs baseline: 1.9608x; 1.9608x over previous
//
#include <hip/hip_runtime.h>

// Problem dims (fp32 in / fp32 out)
#define B_    64
#define T_    512
#define DIN_  256
#define H_    512
#define DOUT_ 128

// Pipeline chunking: layer-1 consumes layer-0's output CHUNK timesteps at a time.
#define CHUNK  32
#define NCHUNK (T_ / CHUNK)     // 16
#define NGEMM  64               // gemm-worker WGs: (B_*CHUNK/128) M-tiles * (H_/128) N-tiles = 16*4

typedef _Float16 f16x8 __attribute__((ext_vector_type(8)));
typedef float    f32x4 __attribute__((ext_vector_type(4)));
typedef _Float16 half2v __attribute__((ext_vector_type(2)));

// ---------------------------------------------------------------------------
// dot of 8 f16 pairs (w,h packed as uint4) accumulated into fp32
__device__ __forceinline__ float dot8(uint4 w, uint4 h, float s) {
#if __has_builtin(__builtin_amdgcn_fdot2)
  s = __builtin_amdgcn_fdot2(__builtin_bit_cast(half2v, w.x), __builtin_bit_cast(half2v, h.x), s, false);
  s = __builtin_amdgcn_fdot2(__builtin_bit_cast(half2v, w.y), __builtin_bit_cast(half2v, h.y), s, false);
  s = __builtin_amdgcn_fdot2(__builtin_bit_cast(half2v, w.z), __builtin_bit_cast(half2v, h.z), s, false);
  s = __builtin_amdgcn_fdot2(__builtin_bit_cast(half2v, w.w), __builtin_bit_cast(half2v, h.w), s, false);
#else
  const half2v* wp = (const half2v*)&w;
  const half2v* hp = (const half2v*)&h;
#pragma unroll
  for (int q = 0; q < 4; ++q) {
    s += (float)wp[q][0] * (float)hp[q][0] + (float)wp[q][1] * (float)hp[q][1];
  }
#endif
  return s;
}

// fast branchless tanh: tanh(x) = sign(x) * (1 - 2/(e^{2|x|}+1)); |err| ~1e-6
__device__ __forceinline__ float fast_tanh(float x) {
  float a = fabsf(x);
  float e = __expf(2.f * a);
  float r = 1.f - 2.f / (e + 1.f);
  return copysignf(r, x);
}

// opaque pin: forces v's components into arch VGPRs at this point and makes
// the producing loads non-rematerializable
__device__ __forceinline__ void pin4(uint4& v) {
  asm volatile("" : "+v"(v.x), "+v"(v.y), "+v"(v.z), "+v"(v.w));
}

// device-scope (agent) flag ops for the chunk pipeline
__device__ __forceinline__ unsigned ld_flag(const unsigned* p) {
  return __hip_atomic_load(p, __ATOMIC_RELAXED, __HIP_MEMORY_SCOPE_AGENT);
}
__device__ __forceinline__ void add_flag(unsigned* p) {
  __hip_atomic_fetch_add(p, 1u, __ATOMIC_RELEASE, __HIP_MEMORY_SCOPE_AGENT);
}
__device__ __forceinline__ void wait_flag(const unsigned* p, unsigned target) {
  // bounded spin: capacity argument guarantees progress (192 WGs <= 256 CUs,
  // producers never wait on consumers); bound converts any surprise into a
  // wrong-answer failure instead of a hang.
  for (int n = 0; n < (1 << 21); ++n) {
    if (ld_flag(p) >= target) return;
    __builtin_amdgcn_s_sleep(8);
  }
}

// ---------------------------------------------------------------------------
// Generic fp32 -> f16 conversion (memory-bound, one-shot prep)
__global__ void cvt_f32_f16(const float* __restrict__ in, _Float16* __restrict__ out, int n) {
  int idx = blockIdx.x * 256 + threadIdx.x;
  if (idx < n) out[idx] = (_Float16)in[idx];
}

__global__ void zero_flags(unsigned* __restrict__ f) {
  if (threadIdx.x < 2 * NCHUNK) f[threadIdx.x] = 0u;
}

// ---------------------------------------------------------------------------
// Prep: convert W_hh (fp32, row-major HxH) into the 8-split scan layout:
// thread tid owns rows 8*(tid&63)+s (s=0..7) over k-eighth u=tid>>6.
// Slot (s,i): slot = s*8+i (i = col-chunk of 8 within the 64-wide eighth).
// chunk c = slot*512 + tid  holds  W[8*(tid&63)+s][(tid>>6)*64 + i*8 .. +8)
// Scan thread tid loads chunk (s,i) at lane-stride 16 B -> fully coalesced.
__global__ void prep_w(const float* __restrict__ w0, const float* __restrict__ w1,
                       _Float16* __restrict__ o0, _Float16* __restrict__ o1) {
  int idx = blockIdx.x * 256 + threadIdx.x;        // 0 .. 65535 (two matrices)
  const float* src = (idx < 32768) ? w0 : w1;
  _Float16* dst = (idx < 32768) ? o0 : o1;
  int c = idx & 32767;
  int tid  = c & 511;
  int slot = c >> 9;          // 0..63
  int i = slot & 7;
  int s = slot >> 3;          // 0..7
  int row = 8 * (tid & 63) + s;
  int kc  = (tid >> 6) * 8 + i;
#pragma unroll
  for (int e = 0; e < 8; ++e)
    dst[(size_t)c * 8 + e] = (_Float16)src[row * 512 + kc * 8 + e];
}

// ---------------------------------------------------------------------------
// GEMM: out[m,n] = sum_k X[m,k]*W[n,k] + bias1[n] + bias2[n], written as f16.
// 128x128 tile / 256 threads / 4 waves (2x2 of 64x64), BK=32 (for xproj0 only).
__global__ __launch_bounds__(256)
void gemm_xproj(const _Float16* __restrict__ X,
                const _Float16* __restrict__ W,
                const float* __restrict__ bias1,
                const float* __restrict__ bias2,
                _Float16* __restrict__ out, int K) {
  __shared__ __align__(16) _Float16 As[128 * 32];
  __shared__ __align__(16) _Float16 Bs[128 * 32];
  const int tid  = threadIdx.x;
  const int wave = tid >> 6;
  const int lane = tid & 63;
  const int wr = wave >> 1, wc = wave & 1;
  const int m0 = blockIdx.x * 128, n0 = blockIdx.y * 128;
  const int fr = lane & 15;
  const int fk = (lane >> 4) * 8;
  const int cA = (lane & 3) * 8;
  const int rsub = lane >> 2;

  f32x4 acc[4][4];
#pragma unroll
  for (int a = 0; a < 4; ++a)
#pragma unroll
    for (int b = 0; b < 4; ++b)
      acc[a][b] = (f32x4){0.f, 0.f, 0.f, 0.f};

  for (int k0 = 0; k0 < K; k0 += 32) {
    __syncthreads();
#pragma unroll
    for (int q = 0; q < 2; ++q) {
      int p = wave * 2 + q;
      int r = p * 16 + rsub;
      const _Float16* gA = X + (size_t)(m0 + r) * K + (k0 + cA);
      const _Float16* gB = W + (size_t)(n0 + r) * K + (k0 + cA);
      __builtin_amdgcn_global_load_lds(
          (const __attribute__((address_space(1))) void*)gA,
          (__attribute__((address_space(3))) void*)((char*)As + p * 1024), 16, 0, 0);
      __builtin_amdgcn_global_load_lds(
          (const __attribute__((address_space(1))) void*)gB,
          (__attribute__((address_space(3))) void*)((char*)Bs + p * 1024), 16, 0, 0);
    }
    __syncthreads();

    f16x8 af[4], bfr[4];
#pragma unroll
    for (int mt = 0; mt < 4; ++mt)
      af[mt] = *(const f16x8*)&As[(wr * 64 + mt * 16 + fr) * 32 + fk];
#pragma unroll
    for (int nt = 0; nt < 4; ++nt)
      bfr[nt] = *(const f16x8*)&Bs[(wc * 64 + nt * 16 + fr) * 32 + fk];
#pragma unroll
    for (int mt = 0; mt < 4; ++mt)
#pragma unroll
      for (int nt = 0; nt < 4; ++nt)
        acc[mt][nt] = __builtin_amdgcn_mfma_f32_16x16x32_f16(af[mt], bfr[nt], acc[mt][nt], 0, 0, 0);
  }

  const int col = lane & 15, rq = lane >> 4;
#pragma unroll
  for (int nt = 0; nt < 4; ++nt) {
    int n = n0 + wc * 64 + nt * 16 + col;
    float bias = bias1[n] + bias2[n];
#pragma unroll
    for (int mt = 0; mt < 4; ++mt) {
      int mbase = m0 + wr * 64 + mt * 16 + rq * 4;
#pragma unroll
      for (int r = 0; r < 4; ++r)
        out[(size_t)(mbase + r) * H_ + n] = (_Float16)(acc[mt][nt][r] + bias);
    }
  }
}

// ---------------------------------------------------------------------------
// Scan role, R4: the 8-split retried at R2's EXACT register budget.
//   8 waves = 8 k-eighths (u = tid>>6), 8 rows/thread (rows 8r+s, r=tid&63),
//   K=64 per thread -> h-broadcast is 8 b128/thread (was 16 in R2).
// Residency identical to R2: 32 reg slots / 6 LDS slots / 26 streamed:
//   slots  0..31 (s=0..3)        -> wreg[32] = 128 VGPR (R2-proven budget)
//   slots 32..37 (s=4, i=0..5)   -> 48 KB LDS
//   slots 38..39 (s=4, i=6..7)   -> q4[2] prefilled per step
//   slots 40..63 (s=5..7)        -> three 3-deep rings (cover ~3 iters)
// All ring loads are consumed before barrier A (no cross-barrier vmem),
// so plain __syncthreads (vmcnt drain) is harmless -> R2's sync structure.
__device__ __forceinline__ void scan_role(
    int layer, int b,
    const uint4* __restrict__ Wg, const _Float16* __restrict__ xproj,
    _Float16* __restrict__ seq, float* __restrict__ hlast,
    unsigned* __restrict__ ca, unsigned* __restrict__ cb, char* smem)
{
  uint4* ldsW = (uint4*)smem;                                  // 48 KB (slots 32..37)
  float* psum = (float*)(smem + 49152);                        // 16 KB [8][512]
  _Float16 (*hb)[512] = (_Float16 (*)[512])(smem + 65536);     // 2 KB h double buffer
  const int tid = threadIdx.x;
  const int u = tid >> 6;                                      // k-eighth 0..7 (= wave)
  const int r = tid & 63;

  // slots 0..31 (s=0..3) -> 128 VGPRs, coalesced (lane stride 16 B)
  uint4 wreg[32];
#pragma unroll
  for (int i = 0; i < 32; ++i) wreg[i] = Wg[i * 512 + tid];
#pragma unroll
  for (int i = 0; i < 32; ++i) pin4(wreg[i]);

  // slots 32..37 (s=4, i=0..5) -> LDS
#pragma unroll
  for (int i = 0; i < 6; ++i) ldsW[i * 512 + tid] = Wg[(32 + i) * 512 + tid];

  hb[0][tid] = (_Float16)0.f;
  hb[1][tid] = (_Float16)0.f;
  __syncthreads();

  const uint4* S4 = Wg + (size_t)38 * 512 + tid;    // s=4, i=6..7 (2 slots)
  const uint4* S5 = Wg + (size_t)40 * 512 + tid;    // s=5, i=0..7
  const uint4* S6 = Wg + (size_t)48 * 512 + tid;    // s=6, i=0..7
  const uint4* S7 = Wg + (size_t)56 * 512 + tid;    // s=7, i=0..7
  const _Float16* xp = xproj + (size_t)b * (T_ * H_) + tid;
  _Float16* sq = seq + (size_t)b * (T_ * H_) + tid;

  int cur = 0;
  for (int t = 0; t < T_; ++t) {
    if (layer == 1 && (t & (CHUNK - 1)) == 0) {
      // acquire chunk t/CHUNK of xproj1
      if (tid == 0) wait_flag(cb + (t / CHUNK), NGEMM);
      __syncthreads();
      __threadfence();                              // inv stale L1/L2 lines
    }
    float xv = (float)xp[(size_t)t * H_];           // consumed after barrier A
    const uint4* hbu = (const uint4*)hb[cur] + u * 8;

    // prefill q4 (2 slots) + prime three 3-deep rings (11 outstanding loads)
    uint4 q4[2], q5[3], q6[3], q7[3];
    q4[0] = S4[0];  q4[1] = S4[512];
#pragma unroll
    for (int p = 0; p < 3; ++p) {
      q5[p] = S5[(size_t)p * 512];
      q6[p] = S6[(size_t)p * 512];
      q7[p] = S7[(size_t)p * 512];
    }

    float a0 = 0.f, a1 = 0.f, a2 = 0.f, a3 = 0.f;
    float a4 = 0.f, a5 = 0.f, a6 = 0.f, a7 = 0.f;   // 8 independent chains
#pragma unroll
    for (int i = 0; i < 8; ++i) {
      uint4 h = hbu[i];                             // one b128 broadcast read
      a0 = dot8(wreg[i],      h, a0);
      a1 = dot8(wreg[8 + i],  h, a1);
      a2 = dot8(wreg[16 + i], h, a2);
      a3 = dot8(wreg[24 + i], h, a3);
      a4 = dot8(i < 6 ? ldsW[i * 512 + tid] : q4[i - 6], h, a4);
      a5 = dot8(q5[i % 3], h, a5);
      if (i < 5) q5[i % 3] = S5[(size_t)(i + 3) * 512];
      a6 = dot8(q6[i % 3], h, a6);
      if (i < 5) q6[i % 3] = S6[(size_t)(i + 3) * 512];
      a7 = dot8(q7[i % 3], h, a7);
      if (i < 5) q7[i % 3] = S7[(size_t)(i + 3) * 512];
    }
    // rows 8r+s: two dense b128 stores into psum[u][8r..8r+7] (2-way, ~free)
    *(f32x4*)&psum[u * 512 + 8 * r]     = (f32x4){a0, a1, a2, a3};
    *(f32x4*)&psum[u * 512 + 8 * r + 4] = (f32x4){a4, a5, a6, a7};
    __syncthreads();                                // A: partials visible

    // reduce: thread tid owns row tid; lane-stride-4B dense (R2's pattern)
    float s = (((psum[tid] + psum[512 + tid]) + (psum[1024 + tid] + psum[1536 + tid])) +
               ((psum[2048 + tid] + psum[2560 + tid]) + (psum[3072 + tid] + psum[3584 + tid])));
    float hn = fast_tanh(s + xv);
    _Float16 h16 = (_Float16)hn;
    hb[cur ^ 1][tid] = h16;
    if (layer == 0) {
      sq[(size_t)t * H_] = h16;
    } else if (t == T_ - 1) {
      hlast[b * H_ + tid] = hn;
    }
    __syncthreads();                                // B: hb[cur^1] + chunk stores drained
    cur ^= 1;
    if (layer == 0 && (t & (CHUNK - 1)) == CHUNK - 1) {
      // barrier B drained every thread's seq stores; flush + publish
      if (tid == 0) { __threadfence(); add_flag(ca + (t / CHUNK)); }
    }
  }
}

// ---------------------------------------------------------------------------
// GEMM worker role: per chunk c, WG g computes one 128x128 tile of
// xproj1 = h1seq @ W_ih1^T + b_ih1 + b_hh1, writing IN PLACE over xproj0
// (safe: runs only after all L0 WGs finished — and thus finished reading —
// chunk c). 512 threads = 8 waves as 4x2 grid of 32x64 fragments.
__device__ __forceinline__ void gemm_role(
    int g,
    const _Float16* __restrict__ X,      // h1seq  (B,T,H) f16
    const _Float16* __restrict__ W,      // W_ih1  (H,H)   f16
    const float* __restrict__ bias1, const float* __restrict__ bias2,
    _Float16* __restrict__ out,          // xproj  (B,T,H) f16 (in-place)
    unsigned* __restrict__ ca, unsigned* __restrict__ cb, char* smem)
{
  _Float16* As = (_Float16*)smem;              // 8 KB [128][32]
  _Float16* Bs = (_Float16*)(smem + 8192);     // 8 KB [128][32]
  const int tid  = threadIdx.x;
  const int wave = tid >> 6;
  const int lane = tid & 63;
  const int wr = wave >> 1, wc = wave & 1;     // 4x2 waves, each 32 rows x 64 cols
  const int mt = g >> 2;                       // M-tile 0..15 (128 rows of 2048)
  const int n0 = (g & 3) * 128;
  const int fr = lane & 15;
  const int fk = (lane >> 4) * 8;
  const int sr  = tid >> 2;                    // staging row 0..127
  const int scq = (tid & 3) * 8;               // staging col (f16) 0/8/16/24
  const int col = lane & 15, rq = lane >> 4;
  const size_t wrow = (size_t)(n0 + sr) * H_ + scq;   // W staging addr (chunk-invariant)

  for (int c = 0; c < NCHUNK; ++c) {
    if (tid == 0) wait_flag(ca + c, B_);       // all 64 L0 WGs done with chunk c
    __syncthreads();
    __threadfence();                           // inv stale lines before reading h1seq

    // tile row jj -> batch 4*mt + (jj>>5), t = c*CHUNK + (jj&31)
    const size_t arow =
        ((size_t)(4 * mt + (sr >> 5)) * T_ + c * CHUNK + (sr & 31)) * H_ + scq;

    f32x4 acc[2][4];
#pragma unroll
    for (int m = 0; m < 2; ++m)
#pragma unroll
      for (int n = 0; n < 4; ++n)
        acc[m][n] = (f32x4){0.f, 0.f, 0.f, 0.f};

    for (int k0 = 0; k0 < H_; k0 += 32) {
      __syncthreads();
      __builtin_amdgcn_global_load_lds(
          (const __attribute__((address_space(1))) void*)(X + arow + k0),
          (__attribute__((address_space(3))) void*)((char*)As + (tid >> 6) * 1024), 16, 0, 0);
      __builtin_amdgcn_global_load_lds(
          (const __attribute__((address_space(1))) void*)(W + wrow + k0),
          (__attribute__((address_space(3))) void*)((char*)Bs + (tid >> 6) * 1024), 16, 0, 0);
      __syncthreads();                         // plain: NEEDS the vmcnt drain

      f16x8 af[2], bf[4];
#pragma unroll
      for (int m = 0; m < 2; ++m)
        af[m] = *(const f16x8*)&As[(wr * 32 + m * 16 + fr) * 32 + fk];
#pragma unroll
      for (int n = 0; n < 4; ++n)
        bf[n] = *(const f16x8*)&Bs[(wc * 64 + n * 16 + fr) * 32 + fk];
#pragma unroll
      for (int m = 0; m < 2; ++m)
#pragma unroll
        for (int n = 0; n < 4; ++n)
          acc[m][n] = __builtin_amdgcn_mfma_f32_16x16x32_f16(af[m], bf[n], acc[m][n], 0, 0, 0);
    }

#pragma unroll
    for (int n = 0; n < 4; ++n) {
      int nn = n0 + wc * 64 + n * 16 + col;
      float bias = bias1[nn] + bias2[nn];
#pragma unroll
      for (int m = 0; m < 2; ++m) {
        int jbase = wr * 32 + m * 16 + rq * 4;
#pragma unroll
        for (int r = 0; r < 4; ++r) {
          int jj = jbase + r;
          size_t row = ((size_t)(4 * mt + (jj >> 5)) * T_ + c * CHUNK + (jj & 31)) * (size_t)H_;
          out[row + nn] = (_Float16)(acc[m][n][r] + bias);
        }
      }
    }
    __syncthreads();                           // drain all threads' tile stores
    if (tid == 0) { __threadfence(); add_flag(cb + c); }
  }
}

// ---------------------------------------------------------------------------
// Fused pipeline megakernel: 192 WGs x 512 threads, __launch_bounds__(512,1).
//   WG   0..63  : layer-0 scan (batch b)       — produces h1seq chunk flags ca[]
//   WG  64..127 : layer-1 scan (batch b-64)    — consumes xproj1 chunk flags cb[]
//   WG 128..191 : GEMM workers                 — ca[c] -> xproj1 tile -> cb[c]
// 192 WGs <= 256 CUs => all co-resident regardless of placement; the wait DAG
// (L1 <- GEMM <- L0, L0 waits on nothing) is therefore deadlock-free.
__global__ __launch_bounds__(512, 1)
void fused_pipeline(const uint4* __restrict__ Wg0, const uint4* __restrict__ Wg1,
                    const _Float16* __restrict__ Wih1,
                    const float* __restrict__ b_ih1, const float* __restrict__ b_hh1,
                    _Float16* __restrict__ xproj, _Float16* __restrict__ h1seq,
                    float* __restrict__ hlast, unsigned* __restrict__ flags) {
  __shared__ __align__(16) char smem[67584];
  unsigned* ca = flags;            // [NCHUNK] target B_
  unsigned* cb = flags + NCHUNK;   // [NCHUNK] target NGEMM
  const int wg = blockIdx.x;
  if (wg < 64) {
    scan_role(0, wg, Wg0, xproj, h1seq, hlast, ca, cb, smem);
  } else if (wg < 128) {
    scan_role(1, wg - 64, Wg1, xproj, h1seq, hlast, ca, cb, smem);
  } else {
    gemm_role(wg - 128, h1seq, Wih1, b_ih1, b_hh1, xproj, ca, cb, smem);
  }
}

// ---------------------------------------------------------------------------
// Final FC: out[b,o] = h2[b,:] . w_fc[o,:] + b_fc[o]   (64 x 128, tiny, pure fp32)
__global__ void fc_kernel(const float* __restrict__ h2,
                          const float* __restrict__ wfc,
                          const float* __restrict__ bfc,
                          float* __restrict__ out) {
  int b = blockIdx.x, o = threadIdx.x;
  float s = bfc[o];
  const float* hv = h2 + b * H_;
  const float* wr = wfc + (size_t)o * H_;
#pragma unroll 8
  for (int k = 0; k < H_; ++k) s += hv[k] * wr[k];
  out[b * DOUT_ + o] = s;
}

// ---------------------------------------------------------------------------
extern "C" void kernel_launch(void* const* d_in, const int* in_sizes, int n_in,
                              void* d_out, int out_size, void* d_ws, size_t ws_size,
                              hipStream_t stream) {
  const float* x     = (const float*)d_in[0];
  const float* w_ih0 = (const float*)d_in[1];
  const float* w_hh0 = (const float*)d_in[2];
  const float* b_ih0 = (const float*)d_in[3];
  const float* b_hh0 = (const float*)d_in[4];
  const float* w_ih1 = (const float*)d_in[5];
  const float* w_hh1 = (const float*)d_in[6];
  const float* b_ih1 = (const float*)d_in[7];
  const float* b_hh1 = (const float*)d_in[8];
  const float* w_fc  = (const float*)d_in[9];
  const float* b_fc  = (const float*)d_in[10];

  char* ws = (char*)d_ws;
  _Float16* Ws0   = (_Float16*)(ws + 0);          // 512 KB  (w_hh0 scan layout)
  _Float16* Ws1   = (_Float16*)(ws + 524288);     // 512 KB  (w_hh1 scan layout)
  _Float16* Wih0  = (_Float16*)(ws + 1048576);    // 256 KB  (w_ih0 f16)
  _Float16* Wih1  = (_Float16*)(ws + 1310720);    // 512 KB  (w_ih1 f16)
  float*    h2    = (float*)   (ws + 2097152);    // 128 KB  (final hidden, fp32)
  unsigned* flags = (unsigned*)(ws + 3145728);    // 128 B   (chunk counters)
  _Float16* xproj = (_Float16*)(ws + 4194304);    // 32 MB   (xproj0, overwritten by xproj1)
  _Float16* xf16  = (_Float16*)(ws + 37748736);   // x as f16, then dead...
  _Float16* h1seq = (_Float16*)(ws + 37748736);   // ...h1 sequence f16 (32 MB)

  // 1) one-shot conversions to f16 + flag reset (re-zeroed every graph iteration)
  cvt_f32_f16<<<32768, 256, 0, stream>>>(x, xf16, B_ * T_ * DIN_);
  cvt_f32_f16<<<512,   256, 0, stream>>>(w_ih0, Wih0, H_ * DIN_);
  cvt_f32_f16<<<1024,  256, 0, stream>>>(w_ih1, Wih1, H_ * H_);
  prep_w<<<256, 256, 0, stream>>>(w_hh0, w_hh1, Ws0, Ws1);
  zero_flags<<<1, 64, 0, stream>>>(flags);

  // 2) xproj0 = x @ w_ih0^T + b_ih0 + b_hh0   (M=32768, K=256)
  gemm_xproj<<<dim3(256, 4), 256, 0, stream>>>(xf16, Wih0, b_ih0, b_hh0, xproj, DIN_);

  // 3+4+5) fused: layer-0 scan || chunked xproj1 GEMM || layer-1 scan
  fused_pipeline<<<192, 512, 0, stream>>>((const uint4*)Ws0, (const uint4*)Ws1,
                                          Wih1, b_ih1, b_hh1,
                                          xproj, h1seq, h2, flags);

  // 6) FC -> d_out (fp32, 64x128)
  fc_kernel<<<B_, DOUT_, 0, stream>>>(h2, w_fc, b_fc, (float*)d_out);
}

// Round 5
// 1202.118 us; speedup vs baseline: 2.4255x; 1.2370x over previous
//
#include <hip/hip_runtime.h>

// Problem dims (fp32 in / fp32 out)
#define B_    64
#define T_    512
#define DIN_  256
#define H_    512
#define DOUT_ 128

// Pipeline chunking: layer-1 consumes layer-0's output CHUNK timesteps at a time.
#define CHUNK  32
#define NCHUNK (T_ / CHUNK)     // 16
#define NGEMM  64               // gemm-worker WGs: (B_*CHUNK/128) M-tiles * (H_/128) N-tiles = 16*4

typedef _Float16 f16x8 __attribute__((ext_vector_type(8)));
typedef float    f32x4 __attribute__((ext_vector_type(4)));
typedef _Float16 half2v __attribute__((ext_vector_type(2)));

// ---------------------------------------------------------------------------
// dot of 8 f16 pairs (w,h packed as uint4) accumulated into fp32
__device__ __forceinline__ float dot8(uint4 w, uint4 h, float s) {
#if __has_builtin(__builtin_amdgcn_fdot2)
  s = __builtin_amdgcn_fdot2(__builtin_bit_cast(half2v, w.x), __builtin_bit_cast(half2v, h.x), s, false);
  s = __builtin_amdgcn_fdot2(__builtin_bit_cast(half2v, w.y), __builtin_bit_cast(half2v, h.y), s, false);
  s = __builtin_amdgcn_fdot2(__builtin_bit_cast(half2v, w.z), __builtin_bit_cast(half2v, h.z), s, false);
  s = __builtin_amdgcn_fdot2(__builtin_bit_cast(half2v, w.w), __builtin_bit_cast(half2v, h.w), s, false);
#else
  const half2v* wp = (const half2v*)&w;
  const half2v* hp = (const half2v*)&h;
#pragma unroll
  for (int q = 0; q < 4; ++q) {
    s += (float)wp[q][0] * (float)hp[q][0] + (float)wp[q][1] * (float)hp[q][1];
  }
#endif
  return s;
}

// fast branchless tanh: tanh(x) = sign(x) * (1 - 2/(e^{2|x|}+1)); |err| ~1e-6
__device__ __forceinline__ float fast_tanh(float x) {
  float a = fabsf(x);
  float e = __expf(2.f * a);
  float r = 1.f - 2.f / (e + 1.f);
  return copysignf(r, x);
}

// opaque pin: forces v's components into arch VGPRs at this point and makes
// the producing loads non-rematerializable
__device__ __forceinline__ void pin4(uint4& v) {
  asm volatile("" : "+v"(v.x), "+v"(v.y), "+v"(v.z), "+v"(v.w));
}

// LDS-only barrier: drains own ds ops (lgkmcnt) then syncs, WITHOUT the
// vmcnt(0) drain __syncthreads emits — in-flight global stores/loads with
// register destinations legally stay outstanding across it. (Proven correct
// in R3; the R3 slowdown was register spill, not this.)
__device__ __forceinline__ void barrier_lds() {
  asm volatile("s_waitcnt lgkmcnt(0)" ::: "memory");
  __builtin_amdgcn_s_barrier();
}

// device-scope (agent) flag ops for the chunk pipeline
__device__ __forceinline__ unsigned ld_flag(const unsigned* p) {
  return __hip_atomic_load(p, __ATOMIC_RELAXED, __HIP_MEMORY_SCOPE_AGENT);
}
__device__ __forceinline__ void add_flag(unsigned* p) {
  __hip_atomic_fetch_add(p, 1u, __ATOMIC_RELEASE, __HIP_MEMORY_SCOPE_AGENT);
}
__device__ __forceinline__ void wait_flag(const unsigned* p, unsigned target) {
  // bounded spin: capacity argument guarantees progress (192 WGs <= 256 CUs,
  // 1 WG/CU forced by 138 KB LDS, producers never wait on consumers).
  for (int n = 0; n < (1 << 21); ++n) {
    if (ld_flag(p) >= target) return;
    __builtin_amdgcn_s_sleep(8);
  }
}

// ---------------------------------------------------------------------------
// Generic fp32 -> f16 conversion (memory-bound, one-shot prep)
__global__ void cvt_f32_f16(const float* __restrict__ in, _Float16* __restrict__ out, int n) {
  int idx = blockIdx.x * 256 + threadIdx.x;
  if (idx < n) out[idx] = (_Float16)in[idx];
}

__global__ void zero_flags(unsigned* __restrict__ f) {
  if (threadIdx.x < 2 * NCHUNK) f[threadIdx.x] = 0u;
}

// ---------------------------------------------------------------------------
// Prep: convert W_hh (fp32, row-major HxH) into the R2 4-split scan layout:
//   chunk c = (rsub*16 + i)*512 + tid  holds  W[4*(tid&127)+rsub][(tid>>7)*128 + i*8 .. +8)
// Scan thread tid loads chunk (rsub,i) at lane-stride 16 B -> fully coalesced.
__global__ void prep_w(const float* __restrict__ w0, const float* __restrict__ w1,
                       _Float16* __restrict__ o0, _Float16* __restrict__ o1) {
  int idx = blockIdx.x * 256 + threadIdx.x;        // 0 .. 65535 (two matrices)
  const float* src = (idx < 32768) ? w0 : w1;
  _Float16* dst = (idx < 32768) ? o0 : o1;
  int c = idx & 32767;
  int tid  = c & 511;
  int rest = c >> 9;          // 0..63
  int i    = rest & 15;
  int rsub = rest >> 4;       // 0..3
  int row = 4 * (tid & 127) + rsub;
  int kc  = (tid >> 7) * 16 + i;
#pragma unroll
  for (int e = 0; e < 8; ++e)
    dst[(size_t)c * 8 + e] = (_Float16)src[row * 512 + kc * 8 + e];
}

// ---------------------------------------------------------------------------
// GEMM: out[m,n] = sum_k X[m,k]*W[n,k] + bias1[n] + bias2[n], written as f16.
// 128x128 tile / 256 threads / 4 waves (2x2 of 64x64), BK=32 (for xproj0 only).
__global__ __launch_bounds__(256)
void gemm_xproj(const _Float16* __restrict__ X,
                const _Float16* __restrict__ W,
                const float* __restrict__ bias1,
                const float* __restrict__ bias2,
                _Float16* __restrict__ out, int K) {
  __shared__ __align__(16) _Float16 As[128 * 32];
  __shared__ __align__(16) _Float16 Bs[128 * 32];
  const int tid  = threadIdx.x;
  const int wave = tid >> 6;
  const int lane = tid & 63;
  const int wr = wave >> 1, wc = wave & 1;
  const int m0 = blockIdx.x * 128, n0 = blockIdx.y * 128;
  const int fr = lane & 15;
  const int fk = (lane >> 4) * 8;
  const int cA = (lane & 3) * 8;
  const int rsub = lane >> 2;

  f32x4 acc[4][4];
#pragma unroll
  for (int a = 0; a < 4; ++a)
#pragma unroll
    for (int b = 0; b < 4; ++b)
      acc[a][b] = (f32x4){0.f, 0.f, 0.f, 0.f};

  for (int k0 = 0; k0 < K; k0 += 32) {
    __syncthreads();
#pragma unroll
    for (int q = 0; q < 2; ++q) {
      int p = wave * 2 + q;
      int r = p * 16 + rsub;
      const _Float16* gA = X + (size_t)(m0 + r) * K + (k0 + cA);
      const _Float16* gB = W + (size_t)(n0 + r) * K + (k0 + cA);
      __builtin_amdgcn_global_load_lds(
          (const __attribute__((address_space(1))) void*)gA,
          (__attribute__((address_space(3))) void*)((char*)As + p * 1024), 16, 0, 0);
      __builtin_amdgcn_global_load_lds(
          (const __attribute__((address_space(1))) void*)gB,
          (__attribute__((address_space(3))) void*)((char*)Bs + p * 1024), 16, 0, 0);
    }
    __syncthreads();

    f16x8 af[4], bfr[4];
#pragma unroll
    for (int mt = 0; mt < 4; ++mt)
      af[mt] = *(const f16x8*)&As[(wr * 64 + mt * 16 + fr) * 32 + fk];
#pragma unroll
    for (int nt = 0; nt < 4; ++nt)
      bfr[nt] = *(const f16x8*)&Bs[(wc * 64 + nt * 16 + fr) * 32 + fk];
#pragma unroll
    for (int mt = 0; mt < 4; ++mt)
#pragma unroll
      for (int nt = 0; nt < 4; ++nt)
        acc[mt][nt] = __builtin_amdgcn_mfma_f32_16x16x32_f16(af[mt], bfr[nt], acc[mt][nt], 0, 0, 0);
  }

  const int col = lane & 15, rq = lane >> 4;
#pragma unroll
  for (int nt = 0; nt < 4; ++nt) {
    int n = n0 + wc * 64 + nt * 16 + col;
    float bias = bias1[n] + bias2[n];
#pragma unroll
    for (int mt = 0; mt < 4; ++mt) {
      int mbase = m0 + wr * 64 + mt * 16 + rq * 4;
#pragma unroll
      for (int r = 0; r < 4; ++r)
        out[(size_t)(mbase + r) * H_ + n] = (_Float16)(acc[mt][nt][r] + bias);
    }
  }
}

// ---------------------------------------------------------------------------
// Scan role, R5: R2's exact 4-split structure with the L2 stream shifted
// into idle LDS capacity, and R3's lean barriers.
//   slots  0..31 (row+0,row+1)   -> wreg[32] = 128 VGPR (R2-proven budget)
//   slots 32..47 (row+2, ALL i)  -> 128 KB LDS-resident (was 6 LDS + 10 L2)
//   slots 48..63 (row+3)         -> streamed from L2, one 4-deep ring (R2's)
// Per-step pipes/CU: L2 128 KB ~980 cyc (was 1590) | LDS ~1150 | VALU ~1300.
// 138 KB LDS also hard-forces 1 WG/CU -> no 2-WG packing skew; register
// pressure DROPS vs R2 (one ring instead of two).
__device__ __forceinline__ void scan_role(
    int layer, int b,
    const uint4* __restrict__ Wg, const _Float16* __restrict__ xproj,
    _Float16* __restrict__ seq, float* __restrict__ hlast,
    unsigned* __restrict__ ca, unsigned* __restrict__ cb, char* smem)
{
  uint4* ldsW = (uint4*)smem;                                  // 128 KB (slots 32..47)
  float (*psum)[512] = (float (*)[512])(smem + 131072);        // 8 KB k-quarter partials
  _Float16 (*hb)[512] = (_Float16 (*)[512])(smem + 139264);    // 2 KB h double buffer
  const int tid = threadIdx.x;
  const int u = tid >> 7;                                      // k-quarter 0..3

  // slots 0..31 (rows +0,+1) -> 128 VGPRs, coalesced (lane stride 16 B)
  uint4 wreg[32];
#pragma unroll
  for (int i = 0; i < 32; ++i) wreg[i] = Wg[i * 512 + tid];
#pragma unroll
  for (int i = 0; i < 32; ++i) pin4(wreg[i]);

  // slots 32..47 (row+2, i=0..15) -> LDS (one-time, coalesced)
#pragma unroll
  for (int i = 0; i < 16; ++i) ldsW[i * 512 + tid] = Wg[(32 + i) * 512 + tid];

  hb[0][tid] = (_Float16)0.f;
  hb[1][tid] = (_Float16)0.f;
  __syncthreads();

  const uint4* S3 = Wg + (size_t)48 * 512 + tid;    // row+3, i=0..15 (16 slots)
  const _Float16* xp = xproj + (size_t)b * (T_ * H_) + tid;
  _Float16* sq = seq + (size_t)b * (T_ * H_) + tid;

  int cur = 0;
  for (int t = 0; t < T_; ++t) {
    if (layer == 1 && (t & (CHUNK - 1)) == 0) {
      // acquire chunk t/CHUNK of xproj1
      if (tid == 0) wait_flag(cb + (t / CHUNK), NGEMM);
      __syncthreads();
      __threadfence();                              // inv stale L1/L2 lines
    }
    float xv = (float)xp[(size_t)t * H_];           // in-register across barrier A
    const uint4* hbu = (const uint4*)hb[cur] + u * 16;

    // prefill the 4-deep ring (4 outstanding loads; 12 reloads in-loop)
    uint4 q3[4];
#pragma unroll
    for (int p = 0; p < 4; ++p) q3[p] = S3[(size_t)p * 512];

    float a0 = 0.f, a1 = 0.f, a2 = 0.f, a3 = 0.f;   // row accumulators = 4 chains
#pragma unroll
    for (int i = 0; i < 16; ++i) {
      uint4 h = hbu[i];                             // one b128 broadcast read
      a0 = dot8(wreg[i], h, a0);
      a1 = dot8(wreg[16 + i], h, a1);
      a2 = dot8(ldsW[i * 512 + tid], h, a2);        // dense 16-B stride, conflict-free
      a3 = dot8(q3[i & 3], h, a3);
      if (i + 4 < 16) q3[i & 3] = S3[(size_t)(i + 4) * 512];
    }
    // psum[u][4r+rsub]: one contiguous b128 per thread, conflict-free
    *(f32x4*)&psum[u][4 * (tid & 127)] = (f32x4){a0, a1, a2, a3};
    barrier_lds();                                  // A: partials visible (DS only)

    // reduce: thread tid owns row tid (lane-stride-4B reads, 2-way = free)
    float s = (psum[0][tid] + psum[1][tid]) + (psum[2][tid] + psum[3][tid]);
    float hn = fast_tanh(s + xv);
    _Float16 h16 = (_Float16)hn;
    hb[cur ^ 1][tid] = h16;
    if (layer == 0) {
      sq[(size_t)t * H_] = h16;
    } else if (t == T_ - 1) {
      hlast[b * H_ + tid] = hn;
    }
    if (layer == 0 && (t & (CHUNK - 1)) == CHUNK - 1) {
      // chunk boundary: drain seq stores (vmcnt) before publishing
      __syncthreads();
      if (tid == 0) { __threadfence(); add_flag(ca + (t / CHUNK)); }
    } else {
      barrier_lds();                                // B: hb[cur^1] complete (DS only)
    }
    cur ^= 1;
  }
}

// ---------------------------------------------------------------------------
// GEMM worker role: per chunk c, WG g computes one 128x128 tile of
// xproj1 = h1seq @ W_ih1^T + b_ih1 + b_hh1, writing IN PLACE over xproj0
// (safe: runs only after all L0 WGs finished — and thus finished reading —
// chunk c). 512 threads = 8 waves as 4x2 grid of 32x64 fragments.
__device__ __forceinline__ void gemm_role(
    int g,
    const _Float16* __restrict__ X,      // h1seq  (B,T,H) f16
    const _Float16* __restrict__ W,      // W_ih1  (H,H)   f16
    const float* __restrict__ bias1, const float* __restrict__ bias2,
    _Float16* __restrict__ out,          // xproj  (B,T,H) f16 (in-place)
    unsigned* __restrict__ ca, unsigned* __restrict__ cb, char* smem)
{
  _Float16* As = (_Float16*)smem;              // 8 KB [128][32]
  _Float16* Bs = (_Float16*)(smem + 8192);     // 8 KB [128][32]
  const int tid  = threadIdx.x;
  const int wave = tid >> 6;
  const int lane = tid & 63;
  const int wr = wave >> 1, wc = wave & 1;     // 4x2 waves, each 32 rows x 64 cols
  const int mt = g >> 2;                       // M-tile 0..15 (128 rows of 2048)
  const int n0 = (g & 3) * 128;
  const int fr = lane & 15;
  const int fk = (lane >> 4) * 8;
  const int sr  = tid >> 2;                    // staging row 0..127
  const int scq = (tid & 3) * 8;               // staging col (f16) 0/8/16/24
  const int col = lane & 15, rq = lane >> 4;
  const size_t wrow = (size_t)(n0 + sr) * H_ + scq;   // W staging addr (chunk-invariant)

  for (int c = 0; c < NCHUNK; ++c) {
    if (tid == 0) wait_flag(ca + c, B_);       // all 64 L0 WGs done with chunk c
    __syncthreads();
    __threadfence();                           // inv stale lines before reading h1seq

    // tile row jj -> batch 4*mt + (jj>>5), t = c*CHUNK + (jj&31)
    const size_t arow =
        ((size_t)(4 * mt + (sr >> 5)) * T_ + c * CHUNK + (sr & 31)) * H_ + scq;

    f32x4 acc[2][4];
#pragma unroll
    for (int m = 0; m < 2; ++m)
#pragma unroll
      for (int n = 0; n < 4; ++n)
        acc[m][n] = (f32x4){0.f, 0.f, 0.f, 0.f};

    for (int k0 = 0; k0 < H_; k0 += 32) {
      __syncthreads();
      __builtin_amdgcn_global_load_lds(
          (const __attribute__((address_space(1))) void*)(X + arow + k0),
          (__attribute__((address_space(3))) void*)((char*)As + (tid >> 6) * 1024), 16, 0, 0);
      __builtin_amdgcn_global_load_lds(
          (const __attribute__((address_space(1))) void*)(W + wrow + k0),
          (__attribute__((address_space(3))) void*)((char*)Bs + (tid >> 6) * 1024), 16, 0, 0);
      __syncthreads();                         // plain: NEEDS the vmcnt drain

      f16x8 af[2], bf[4];
#pragma unroll
      for (int m = 0; m < 2; ++m)
        af[m] = *(const f16x8*)&As[(wr * 32 + m * 16 + fr) * 32 + fk];
#pragma unroll
      for (int n = 0; n < 4; ++n)
        bf[n] = *(const f16x8*)&Bs[(wc * 64 + n * 16 + fr) * 32 + fk];
#pragma unroll
      for (int m = 0; m < 2; ++m)
#pragma unroll
        for (int n = 0; n < 4; ++n)
          acc[m][n] = __builtin_amdgcn_mfma_f32_16x16x32_f16(af[m], bf[n], acc[m][n], 0, 0, 0);
    }

#pragma unroll
    for (int n = 0; n < 4; ++n) {
      int nn = n0 + wc * 64 + n * 16 + col;
      float bias = bias1[nn] + bias2[nn];
#pragma unroll
      for (int m = 0; m < 2; ++m) {
        int jbase = wr * 32 + m * 16 + rq * 4;
#pragma unroll
        for (int r = 0; r < 4; ++r) {
          int jj = jbase + r;
          size_t row = ((size_t)(4 * mt + (jj >> 5)) * T_ + c * CHUNK + (jj & 31)) * (size_t)H_;
          out[row + nn] = (_Float16)(acc[m][n][r] + bias);
        }
      }
    }
    __syncthreads();                           // drain all threads' tile stores
    if (tid == 0) { __threadfence(); add_flag(cb + c); }
  }
}

// ---------------------------------------------------------------------------
// Fused pipeline megakernel: 192 WGs x 512 threads, __launch_bounds__(512,1).
//   WG   0..63  : layer-0 scan (batch b)       — produces h1seq chunk flags ca[]
//   WG  64..127 : layer-1 scan (batch b-64)    — consumes xproj1 chunk flags cb[]
//   WG 128..191 : GEMM workers                 — ca[c] -> xproj1 tile -> cb[c]
// 138 KB LDS forces 1 WG/CU: 192 WGs <= 256 CUs all co-resident, one per CU;
// the wait DAG (L1 <- GEMM <- L0, L0 waits on nothing) is deadlock-free.
__global__ __launch_bounds__(512, 1)
void fused_pipeline(const uint4* __restrict__ Wg0, const uint4* __restrict__ Wg1,
                    const _Float16* __restrict__ Wih1,
                    const float* __restrict__ b_ih1, const float* __restrict__ b_hh1,
                    _Float16* __restrict__ xproj, _Float16* __restrict__ h1seq,
                    float* __restrict__ hlast, unsigned* __restrict__ flags) {
  __shared__ __align__(16) char smem[141312];
  unsigned* ca = flags;            // [NCHUNK] target B_
  unsigned* cb = flags + NCHUNK;   // [NCHUNK] target NGEMM
  const int wg = blockIdx.x;
  if (wg < 64) {
    scan_role(0, wg, Wg0, xproj, h1seq, hlast, ca, cb, smem);
  } else if (wg < 128) {
    scan_role(1, wg - 64, Wg1, xproj, h1seq, hlast, ca, cb, smem);
  } else {
    gemm_role(wg - 128, h1seq, Wih1, b_ih1, b_hh1, xproj, ca, cb, smem);
  }
}

// ---------------------------------------------------------------------------
// Final FC: out[b,o] = h2[b,:] . w_fc[o,:] + b_fc[o]   (64 x 128, tiny, pure fp32)
__global__ void fc_kernel(const float* __restrict__ h2,
                          const float* __restrict__ wfc,
                          const float* __restrict__ bfc,
                          float* __restrict__ out) {
  int b = blockIdx.x, o = threadIdx.x;
  float s = bfc[o];
  const float* hv = h2 + b * H_;
  const float* wr = wfc + (size_t)o * H_;
#pragma unroll 8
  for (int k = 0; k < H_; ++k) s += hv[k] * wr[k];
  out[b * DOUT_ + o] = s;
}

// ---------------------------------------------------------------------------
extern "C" void kernel_launch(void* const* d_in, const int* in_sizes, int n_in,
                              void* d_out, int out_size, void* d_ws, size_t ws_size,
                              hipStream_t stream) {
  const float* x     = (const float*)d_in[0];
  const float* w_ih0 = (const float*)d_in[1];
  const float* w_hh0 = (const float*)d_in[2];
  const float* b_ih0 = (const float*)d_in[3];
  const float* b_hh0 = (const float*)d_in[4];
  const float* w_ih1 = (const float*)d_in[5];
  const float* w_hh1 = (const float*)d_in[6];
  const float* b_ih1 = (const float*)d_in[7];
  const float* b_hh1 = (const float*)d_in[8];
  const float* w_fc  = (const float*)d_in[9];
  const float* b_fc  = (const float*)d_in[10];

  char* ws = (char*)d_ws;
  _Float16* Ws0   = (_Float16*)(ws + 0);          // 512 KB  (w_hh0 scan layout)
  _Float16* Ws1   = (_Float16*)(ws + 524288);     // 512 KB  (w_hh1 scan layout)
  _Float16* Wih0  = (_Float16*)(ws + 1048576);    // 256 KB  (w_ih0 f16)
  _Float16* Wih1  = (_Float16*)(ws + 1310720);    // 512 KB  (w_ih1 f16)
  float*    h2    = (float*)   (ws + 2097152);    // 128 KB  (final hidden, fp32)
  unsigned* flags = (unsigned*)(ws + 3145728);    // 128 B   (chunk counters)
  _Float16* xproj = (_Float16*)(ws + 4194304);    // 32 MB   (xproj0, overwritten by xproj1)
  _Float16* xf16  = (_Float16*)(ws + 37748736);   // x as f16, then dead...
  _Float16* h1seq = (_Float16*)(ws + 37748736);   // ...h1 sequence f16 (32 MB)

  // 1) one-shot conversions to f16 + flag reset (re-zeroed every graph iteration)
  cvt_f32_f16<<<32768, 256, 0, stream>>>(x, xf16, B_ * T_ * DIN_);
  cvt_f32_f16<<<512,   256, 0, stream>>>(w_ih0, Wih0, H_ * DIN_);
  cvt_f32_f16<<<1024,  256, 0, stream>>>(w_ih1, Wih1, H_ * H_);
  prep_w<<<256, 256, 0, stream>>>(w_hh0, w_hh1, Ws0, Ws1);
  zero_flags<<<1, 64, 0, stream>>>(flags);

  // 2) xproj0 = x @ w_ih0^T + b_ih0 + b_hh0   (M=32768, K=256)
  gemm_xproj<<<dim3(256, 4), 256, 0, stream>>>(xf16, Wih0, b_ih0, b_hh0, xproj, DIN_);

  // 3+4+5) fused: layer-0 scan || chunked xproj1 GEMM || layer-1 scan
  fused_pipeline<<<192, 512, 0, stream>>>((const uint4*)Ws0, (const uint4*)Ws1,
                                          Wih1, b_ih1, b_hh1,
                                          xproj, h1seq, h2, flags);

  // 6) FC -> d_out (fp32, 64x128)
  fc_kernel<<<B_, DOUT_, 0, stream>>>(h2, w_fc, b_fc, (float*)d_out);
}